// Round 17
// baseline (520.776 us; speedup 1.0000x reference)
//
#include <hip/hip_runtime.h>
#include <hip/hip_bf16.h>
#include <math.h>

constexpr int B = 8, C = 128, H = 256, W = 256, NN = 256, KNN = 5;
constexpr int HW = H * W;

// ws float offsets
constexpr int WS_ROWSUM = 0;      // 2048 floats
constexpr int WS_COLSUM = 2048;   // 2048
constexpr int WS_GMUL   = 4096;   // 2048  (1 + gate)
constexpr int WS_SCALE  = 6144;   // 128
constexpr int WS_BIAS   = 6272;   // 128
constexpr int WS_PART   = 8192;   // [128 c][64 slot][2] = 16384 floats
constexpr int WS_WT     = 24576;  // conv3 bf16 weights: 36*128*32 ushort
constexpr int WS_W2T    = 98304;  // conv1 bf16 weights: 4*128*32 ushort
constexpr size_t WS_Y_BYTES_OFF = 512 * 1024;

// padded y2p[b][hp=258][c8=16][wp=258][8] bf16, borders (hp/wp = 0,257) zero
constexpr int Y2P_CS = 258 * 8;            // 2064 shorts per c8 row
constexpr int Y2P_HS = 16 * Y2P_CS;        // 33024 shorts per hp
constexpr int Y2P_BS = 258 * Y2P_HS;       // 8,520,192 shorts per b
constexpr size_t Y2P_BYTES = (size_t)B * Y2P_BS * 2;  // 136,323,072

// h is stored as bf16 in the LOWER HALF of each 128-px f32 segment of d_out
// (block-disjoint with the f32 out write -> in-place discipline unchanged).

typedef __attribute__((ext_vector_type(8))) short bf16x8;
typedef __attribute__((ext_vector_type(4))) float f32x4;

union U4 { uint4 q; bf16x8 v; unsigned short u[8]; };

typedef const __attribute__((address_space(1))) unsigned char* gas1;
typedef __attribute__((address_space(3))) unsigned char* las3;
__device__ __forceinline__ void gl_lds16(const void* g, void* l) {
    __builtin_amdgcn_global_load_lds((gas1)g, (las3)l, 16, 0, 0);
}

__device__ inline unsigned short f2bf(float f) {
    __hip_bfloat16 h = __float2bfloat16(f);
    return *reinterpret_cast<unsigned short*>(&h);
}
__device__ inline float bf2f(unsigned short u) {
    __hip_bfloat16 h = *reinterpret_cast<__hip_bfloat16*>(&u);
    return __bfloat162float(h);
}

// ---------------- fused row+col sums (one pass over x) ---------------------
__global__ __launch_bounds__(256) void k_sums(const float* __restrict__ x,
                                              float* __restrict__ ws) {
    const int b = blockIdx.x >> 7;
    const int c = blockIdx.x & 127;
    const int t = threadIdx.x;
    const int wv = t >> 6;
    const float4* p4 = (const float4*)(x + (size_t)(b * C + c) * HW);
    __shared__ float srow[256];
    __shared__ float scol[4][256];
    float ca0 = 0.f, ca1 = 0.f, ca2 = 0.f, ca3 = 0.f;
    for (int it = 0; it < 64; ++it) {
        const float4 v = p4[it * 256 + t];
        ca0 += v.x; ca1 += v.y; ca2 += v.z; ca3 += v.w;
        float s = v.x + v.y + v.z + v.w;
#pragma unroll
        for (int m = 1; m < 64; m <<= 1) s += __shfl_xor(s, m);
        if ((t & 63) == 0) srow[it * 4 + wv] = s;
    }
    const int cb = (t & 63) * 4;
    scol[wv][cb + 0] = ca0;
    scol[wv][cb + 1] = ca1;
    scol[wv][cb + 2] = ca2;
    scol[wv][cb + 3] = ca3;
    __syncthreads();
    atomicAdd(&ws[WS_ROWSUM + b * 256 + t], srow[t]);
    atomicAdd(&ws[WS_COLSUM + b * 256 + t],
              scol[0][t] + scol[1][t] + scol[2][t] + scol[3][t]);
}

// ---------------- gate -----------------------------------------------------
__global__ void k_gate(float* __restrict__ ws) {
    const int b = blockIdx.x;
    const int i = threadIdx.x;
    __shared__ float xm[256], sgn[256];
    const float v = ws[WS_ROWSUM + b * 256 + i] * (1.f / 32768.f)
                  + ws[WS_COLSUM + b * 256 + i] * (1.f / 32768.f);
    xm[i] = v;
    const float vv = v * 0.5f;
    sgn[i] = vv / fmaxf(fabsf(vv), 1e-12f);
    __syncthreads();
    const float si = sgn[i];
    float bd[KNN];
    int bi[KNN];
    for (int k = 0; k < KNN; ++k) { bd[k] = 1e30f; bi[k] = 0; }
    for (int j = 0; j < NN; ++j) {
        float d = si - sgn[j];
        d *= d;
        if (d < bd[KNN - 1]) {
            int p = KNN - 1;
            while (p > 0 && bd[p - 1] > d) {
                bd[p] = bd[p - 1];
                bi[p] = bi[p - 1];
                --p;
            }
            bd[p] = d;
            bi[p] = j;
        }
    }
    float gs = 0.f;
    for (int k = 0; k < KNN; ++k) gs += xm[bi[k]];
    const float gate = 1.f / (1.f + expf(-gs));
    ws[WS_GMUL + b * 256 + i] = 1.f + gate;
}

// ---------------- zero the y2p borders (rows hp=0,257; cols wp=0,257) ------
__global__ __launch_bounds__(256) void k_yzero(unsigned short* __restrict__ y) {
    const int id = blockIdx.x * 256 + threadIdx.x;  // uint4 slot
    const uint4 z = {0u, 0u, 0u, 0u};
    if (id < 66048) {  // 8 b x 2 rows x 4128 uint4
        const int per = Y2P_HS / 8;  // 4128
        const int b = id / (2 * per);
        const int r = id % (2 * per);
        const int hp = (r >= per) ? 257 : 0;
        const int off = (r >= per) ? r - per : r;
        *reinterpret_cast<uint4*>(y + (size_t)b * Y2P_BS + (size_t)hp * Y2P_HS + off * 8) = z;
    } else {
        const int id2 = id - 66048;  // 8 b x 256 hp x 16 c8 x 2 cols
        const int b = id2 >> 13;
        const int r = id2 & 8191;
        const int hp = (r >> 5) + 1;
        const int c8 = (r >> 1) & 15;
        const int wp = (r & 1) ? 257 : 0;
        *reinterpret_cast<uint4*>(y + (size_t)b * Y2P_BS + (size_t)hp * Y2P_HS
                                  + c8 * Y2P_CS + wp * 8) = z;
    }
}

// -------- y gen into padded layout: y2p[b][h+1][c8][w+1][8] ----------------
__global__ __launch_bounds__(256) void k_ygenT(const float* __restrict__ x,
                                               const float* __restrict__ ws,
                                               unsigned short* __restrict__ y) {
    const int b = blockIdx.x >> 8;
    const int h = blockIdx.x & 255;
    const int w = threadIdx.x;
    const float g = ws[WS_GMUL + b * 256 + h];
    const float* xp = x + ((size_t)(b * C) * H + h) * W + w;
    unsigned short* yp = y + (size_t)b * Y2P_BS + (size_t)(h + 1) * Y2P_HS + (w + 1) * 8;
    for (int c8 = 0; c8 < 16; ++c8) {
        U4 pk;
#pragma unroll
        for (int j = 0; j < 8; ++j)
            pk.u[j] = f2bf(xp[(size_t)(c8 * 8 + j) * HW] * g);
        *reinterpret_cast<uint4*>(yp + c8 * Y2P_CS) = pk.q;
    }
}

// ---------------- conv3 weight pre-transform to bf16 [s][och][k] -----------
__global__ void k_wprep(const float* __restrict__ w1, unsigned short* __restrict__ wt) {
    const int e = blockIdx.x * 256 + threadIdx.x;  // 576*256 = 147456
    const int j = e & 7;
    const int kg = (e >> 3) & 3;
    const int och = (e >> 5) & 127;
    const int s = e >> 12;
    const int c = (s & 3) * 32 + kg * 8 + j;
    const int pos = s >> 2;
    const int ky = pos / 3, kx = pos - ky * 3;
    wt[e] = f2bf(w1[(((size_t)och * C + c) * 3 + ky) * 3 + kx]);
}

// ---------------- conv1 weight bf16 [s][och][32], c = s*32+kk --------------
__global__ void k_wprep2(const float* __restrict__ w2, unsigned short* __restrict__ w2t) {
    const int e = blockIdx.x * 256 + threadIdx.x;  // 64*256 = 16384
    const int kk = e & 31;
    const int och = (e >> 5) & 127;
    const int s = e >> 12;
    w2t[e] = f2bf(w2[och * C + s * 32 + kk]);
}

// ========== conv3: 1-barrier/tile, counted vmcnt, 4-buffer B, A in regs ====
// Per tile t: stageB(t+2) -> bufB[(t+2)&3]; loadA(t+1) -> alternating reg
// set; s_waitcnt vmcnt(N) (N=6 steady: B(t) staged 2 ahead + A(t) loaded 1
// ahead stay countable); ONE s_barrier (B(t) visibility; the PREVIOUS tile's
// barrier provides the WAR separation for the 4-deep rotation: buf[(t+2)&3]
// was last read by compute(t-2), and tile t-1's barrier sits between);
// compute. Compiler guarantees A-reg readiness via its own vmcnt insertion.
// B keeps the R16 bank swizzle (src k16s / read lqs). Math order unchanged.
__global__ __launch_bounds__(256) void k_conv3g(const unsigned short* __restrict__ y2,
                                                const unsigned short* __restrict__ wt,
                                                float* __restrict__ ws,
                                                float* __restrict__ hout) {
    // XCD-contiguous swizzle: 4096 blocks = 8 XCDs x 512
    const int bx0 = blockIdx.x;
    const int bx = (bx0 & 7) * 512 + (bx0 >> 3);
    const int whalf = bx & 1;
    const int hrow = (bx >> 1) & 255;
    const int b = bx >> 9;
    const int w0 = whalf * 128;

    const int t = threadIdx.x;
    const int wv = t >> 6;
    const int l = t & 63;
    const int wm = wv >> 1, wn = wv & 1;
    const int lr = l & 15, lq = l >> 4;

    __shared__ __attribute__((aligned(16))) unsigned short sB[4][4096];  // [128 px][32 k]
    __shared__ float sPart[4][128][2];

    f32x4 acc[4][4];
#pragma unroll
    for (int i = 0; i < 4; ++i)
#pragma unroll
        for (int j = 0; j < 4; ++j) acc[i][j] = (f32x4){0.f, 0.f, 0.f, 0.f};

    const char* y2b = (const char*)y2 + (size_t)b * Y2P_BS * 2;
    // bank swizzle (R16): staged k-chunk permuted by k16s; read with lqs.
    const int k16s = (l & 3) ^ ((l >> 3) & 3);
    const int pxl = wv * 16 + (l >> 2);
    const unsigned bLane0 = (unsigned)((pxl * 8 + k16s * Y2P_CS) * 2);
    const unsigned bLane1 = (unsigned)(((pxl + 64) * 8 + k16s * Y2P_CS) * 2);
    // A direct-read base (R13-proven layout)
    const unsigned short* aPtr = wt + (size_t)(wm * 64 + lr) * 32 + lq * 8;

    auto stageB = [&](int s, char* sBp) {
        const int pos = s >> 2, cc = s & 3;
        const int ky = pos / 3, kx = pos - 3 * ky;
        const char* bSrc = y2b + (size_t)((hrow + ky) * Y2P_HS + cc * 4 * Y2P_CS
                                          + (w0 + kx) * 8) * 2;
        gl_lds16(bSrc + bLane0, sBp + wv * 1024);
        gl_lds16(bSrc + bLane1, sBp + 4096 + wv * 1024);
    };
    auto loadA = [&](int s, uint4* d) {
        const unsigned short* p = aPtr + (size_t)s * 4096;
#pragma unroll
        for (int mf = 0; mf < 4; ++mf)
            d[mf] = *reinterpret_cast<const uint4*>(p + mf * 512);
    };
    auto compute = [&](const unsigned short* bT, uint4* aR) {
        const int lqs = lq ^ ((lr >> 1) & 3);
        const unsigned short* bRd = bT + (wn * 64 + lr) * 32 + lqs * 8;
        bf16x8 bfr[4];
#pragma unroll
        for (int nf = 0; nf < 4; ++nf)
            bfr[nf] = *reinterpret_cast<const bf16x8*>(bRd + nf * 512);
#pragma unroll
        for (int mf = 0; mf < 4; ++mf) {
            U4 am; am.q = aR[mf];
#pragma unroll
            for (int nf = 0; nf < 4; ++nf)
                acc[mf][nf] = __builtin_amdgcn_mfma_f32_16x16x32_bf16(
                    am.v, bfr[nf], acc[mf][nf], 0, 0, 0);
        }
    };

    uint4 a0[4], a1[4];
    // prologue: B for tiles 0,1; A for tile 0
    stageB(0, (char*)sB[0]);
    stageB(1, (char*)sB[1]);
    loadA(0, a0);

#define TILE_BODY(T, BUF, ASET_LD, ASET_CP, WAITN)                       \
    {                                                                    \
        if ((T) + 2 < 36) stageB((T) + 2, (char*)sB[((T) + 2) & 3]);     \
        if ((T) + 1 < 36) loadA((T) + 1, ASET_LD);                       \
        asm volatile("s_waitcnt vmcnt(" #WAITN ")" ::: "memory");        \
        __builtin_amdgcn_s_barrier();                                    \
        compute(sB[(BUF)], ASET_CP);                                     \
    }

    for (int s = 0; s < 32; s += 4) {
        TILE_BODY(s + 0, (s + 0) & 3, a1, a0, 6)
        TILE_BODY(s + 1, (s + 1) & 3, a0, a1, 6)
        TILE_BODY(s + 2, (s + 2) & 3, a1, a0, 6)
        TILE_BODY(s + 3, (s + 3) & 3, a0, a1, 6)
    }
    // peeled tail: tiles 32..35 (stage 34,35 valid; 36,37 skipped)
    TILE_BODY(32, 0, a1, a0, 6)
    TILE_BODY(33, 1, a0, a1, 6)
    TILE_BODY(34, 2, a1, a0, 4)   // no stage(36); newer ops = loadA(35) only
    TILE_BODY(35, 3, a0, a1, 0)   // nothing newer
#undef TILE_BODY

    // store h as bf16 packed into the LOW HALF of this 128-px f32 segment.
    // D layout col=lane&15, row=(lane>>4)*4+reg (HW-verified m89).
#pragma unroll
    for (int mf = 0; mf < 4; ++mf) {
#pragma unroll
        for (int reg = 0; reg < 4; ++reg) {
            const int och = wm * 64 + mf * 16 + lq * 4 + reg;
            unsigned short* hseg = reinterpret_cast<unsigned short*>(
                hout + (((size_t)(b * C + och) * H + hrow) * W) + w0);
#pragma unroll
            for (int nf = 0; nf < 4; ++nf)
                hseg[wn * 64 + nf * 16 + lr] = f2bf(acc[mf][nf][reg]);
        }
    }

    // fused BN partial stats (from f32 acc)
#pragma unroll
    for (int mf = 0; mf < 4; ++mf) {
#pragma unroll
        for (int reg = 0; reg < 4; ++reg) {
            float s = 0.f, q = 0.f;
#pragma unroll
            for (int nf = 0; nf < 4; ++nf) {
                const float v = acc[mf][nf][reg];
                s += v;
                q = fmaf(v, v, q);
            }
#pragma unroll
            for (int m = 1; m < 16; m <<= 1) {
                s += __shfl_xor(s, m);
                q += __shfl_xor(q, m);
            }
            if (lr == 0) {
                const int och = wm * 64 + mf * 16 + lq * 4 + reg;
                sPart[wv][och][0] = s;
                sPart[wv][och][1] = q;
            }
        }
    }
    __syncthreads();
    {
        const int o = t & 127;
        const int which = t >> 7;
        const int wmn = o >> 6;
        const float v = sPart[wmn * 2][o][which] + sPart[wmn * 2 + 1][o][which];
        atomicAdd(&ws[WS_PART + o * 128 + (bx & 63) * 2 + which], v);
    }
}

// ---------------- SLOW-PATH conv3 (reads f32 x; bf16 h store) --------------
__device__ inline bf16x8 b_fetch(const float* __restrict__ x, int b, int s,
                                 int hrow, int w0, int px, int kg,
                                 float g0, float g1, float g2) {
    const int pos = s >> 2;
    const int ky = pos / 3, kx = pos - ky * 3;
    const int cbase = (s & 3) * 32 + kg * 8;
    int crow = hrow + ky - 1;
    int col = w0 + px + kx - 1;
    const float g = (ky == 0) ? g0 : ((ky == 1) ? g1 : g2);
    const float sc = ((unsigned)col < (unsigned)W) ? g : 0.f;
    crow = min(max(crow, 0), H - 1);
    col = min(max(col, 0), W - 1);
    const float* p = x + (((size_t)(b * C + cbase) * H + crow) * W + col);
    union { bf16x8 v8; unsigned short u[8]; } r;
#pragma unroll
    for (int j = 0; j < 8; ++j) r.u[j] = f2bf(p[(size_t)j * HW] * sc);
    return r.v8;
}

__global__ __launch_bounds__(256) void k_conv3(const float* __restrict__ x,
                                               const unsigned short* __restrict__ wt,
                                               float* __restrict__ ws,
                                               float* __restrict__ hout) {
    const int bx = blockIdx.x;
    const int whalf = bx & 1;
    const int hrow = (bx >> 1) & 255;
    const int b = bx >> 9;
    const int w0 = whalf * 128;

    const int t = threadIdx.x;
    const int wv = t >> 6;
    const int l = t & 63;
    const int wm = wv >> 1, wn = wv & 1;
    const int lr = l & 15, lq = l >> 4;

    __shared__ unsigned short sA[128 * 40];
    __shared__ unsigned short sB[128 * 40];
    __shared__ float sPart[4][128][2];

    float g0, g1, g2;
    {
        const int r0 = hrow - 1, r2 = hrow + 1;
        g0 = (r0 >= 0) ? ws[WS_GMUL + b * 256 + r0] : 0.f;
        g1 = ws[WS_GMUL + b * 256 + hrow];
        g2 = (r2 < H) ? ws[WS_GMUL + b * 256 + r2] : 0.f;
    }

    f32x4 acc[4][4];
#pragma unroll
    for (int i = 0; i < 4; ++i)
#pragma unroll
        for (int j = 0; j < 4; ++j) acc[i][j] = (f32x4){0.f, 0.f, 0.f, 0.f};

    const int a_och = t & 127, a_h = t >> 7;
    const int b_px = t & 127, b_kg0 = t >> 7;
    const int b_kg1 = b_kg0 + 2;

    uint4 pa0, pa1;
    bf16x8 pb0, pb1;
    {
        const uint4* asrc = reinterpret_cast<const uint4*>(wt + (size_t)a_och * 32 + a_h * 16);
        pa0 = asrc[0];
        pa1 = asrc[1];
        pb0 = b_fetch(x, b, 0, hrow, w0, b_px, b_kg0, g0, g1, g2);
        pb1 = b_fetch(x, b, 0, hrow, w0, b_px, b_kg1, g0, g1, g2);
    }

    for (int s = 0; s < 36; ++s) {
        __syncthreads();
        *reinterpret_cast<uint4*>(&sA[a_och * 40 + a_h * 16]) = pa0;
        *reinterpret_cast<uint4*>(&sA[a_och * 40 + a_h * 16 + 8]) = pa1;
        *reinterpret_cast<bf16x8*>(&sB[b_px * 40 + b_kg0 * 8]) = pb0;
        *reinterpret_cast<bf16x8*>(&sB[b_px * 40 + b_kg1 * 8]) = pb1;
        __syncthreads();

        if (s + 1 < 36) {
            const uint4* asrc = reinterpret_cast<const uint4*>(
                wt + (size_t)(s + 1) * 4096 + (size_t)a_och * 32 + a_h * 16);
            pa0 = asrc[0];
            pa1 = asrc[1];
            pb0 = b_fetch(x, b, s + 1, hrow, w0, b_px, b_kg0, g0, g1, g2);
            pb1 = b_fetch(x, b, s + 1, hrow, w0, b_px, b_kg1, g0, g1, g2);
        }

        bf16x8 af[4], bfr[4];
#pragma unroll
        for (int mf = 0; mf < 4; ++mf) {
            const int och = wm * 64 + mf * 16 + lr;
            af[mf] = *reinterpret_cast<const bf16x8*>(&sA[och * 40 + lq * 8]);
        }
#pragma unroll
        for (int nf = 0; nf < 4; ++nf) {
            const int px = wn * 64 + nf * 16 + lr;
            bfr[nf] = *reinterpret_cast<const bf16x8*>(&sB[px * 40 + lq * 8]);
        }
#pragma unroll
        for (int mf = 0; mf < 4; ++mf)
#pragma unroll
            for (int nf = 0; nf < 4; ++nf)
                acc[mf][nf] = __builtin_amdgcn_mfma_f32_16x16x32_bf16(
                    af[mf], bfr[nf], acc[mf][nf], 0, 0, 0);
    }

#pragma unroll
    for (int mf = 0; mf < 4; ++mf) {
#pragma unroll
        for (int reg = 0; reg < 4; ++reg) {
            const int och = wm * 64 + mf * 16 + lq * 4 + reg;
            unsigned short* hseg = reinterpret_cast<unsigned short*>(
                hout + (((size_t)(b * C + och) * H + hrow) * W) + w0);
#pragma unroll
            for (int nf = 0; nf < 4; ++nf)
                hseg[wn * 64 + nf * 16 + lr] = f2bf(acc[mf][nf][reg]);
        }
    }

#pragma unroll
    for (int mf = 0; mf < 4; ++mf) {
#pragma unroll
        for (int reg = 0; reg < 4; ++reg) {
            float s = 0.f, q = 0.f;
#pragma unroll
            for (int nf = 0; nf < 4; ++nf) {
                const float v = acc[mf][nf][reg];
                s += v;
                q = fmaf(v, v, q);
            }
#pragma unroll
            for (int m = 1; m < 16; m <<= 1) {
                s += __shfl_xor(s, m);
                q += __shfl_xor(q, m);
            }
            if (lr == 0) {
                const int och = wm * 64 + mf * 16 + lq * 4 + reg;
                sPart[wv][och][0] = s;
                sPart[wv][och][1] = q;
            }
        }
    }
    __syncthreads();
    {
        const int o = t & 127;
        const int which = t >> 7;
        const int wmn = o >> 6;
        const float v = sPart[wmn * 2][o][which] + sPart[wmn * 2 + 1][o][which];
        atomicAdd(&ws[WS_PART + o * 128 + (bx & 63) * 2 + which], v);
    }
}

// ---------------- BN scale/bias from partials ------------------------------
__global__ void k_scalebias(const float* __restrict__ gamma,
                            const float* __restrict__ beta, float* __restrict__ ws) {
    const int c = threadIdx.x;
    const float* p = ws + WS_PART + c * 128;
    float s = 0.f, q = 0.f;
    for (int i = 0; i < 64; ++i) {
        s += p[i * 2];
        q += p[i * 2 + 1];
    }
    const float cnt = (float)B * HW;
    const float mu = s / cnt;
    const float var = q / cnt - mu * mu;
    const float rs = rsqrtf(var + 1e-5f);
    const float sc = rs * gamma[c];
    ws[WS_SCALE + c] = sc;
    ws[WS_BIAS + c] = beta[c] - mu * sc;
}

// ========== conv1: plain bf16 operands, K=128 (4 steps), in place ==========
__global__ __launch_bounds__(256) void k_conv1d(float* __restrict__ io,
                                                const unsigned short* __restrict__ w2t,
                                                const float* __restrict__ ws) {
    const int bx = blockIdx.x;
    const int pblk = bx & 511;
    const int b = bx >> 9;
    const size_t p0 = (size_t)pblk * 128;

    const int t = threadIdx.x;
    const int wv = t >> 6;
    const int l = t & 63;
    const int wm = wv >> 1, wn = wv & 1;
    const int lr = l & 15, lq = l >> 4;

    __shared__ float sSB[128][2];
    if (t < 128) {
        sSB[t][0] = ws[WS_SCALE + t];
        sSB[t][1] = ws[WS_BIAS + t];
    }
    __syncthreads();

    f32x4 acc[4][4];
#pragma unroll
    for (int i = 0; i < 4; ++i)
#pragma unroll
        for (int j = 0; j < 4; ++j) acc[i][j] = (f32x4){0.f, 0.f, 0.f, 0.f};

    const unsigned aoff = (unsigned)((wm * 64 + lr) * 32 + lq * 8);
    const float* hbase_f = io + (size_t)b * C * HW + p0;  // + c*HW per channel
    const int segoff = wn * 64 + lr;                      // + nf*16

    uint4 pa0[4], pb0[4], pa1[4], pb1[4];

    auto loadA = [&](int s, uint4* d) {
        const unsigned so = aoff + (unsigned)(s * 4096);
#pragma unroll
        for (int mf = 0; mf < 4; ++mf)
            d[mf] = *reinterpret_cast<const uint4*>(w2t + so + mf * 512);
    };
    // B frag: lane needs channels c = s*32 + lq*8 + j (j=0..7) at its pixel.
    auto loadB = [&](int s, uint4* d) {
        const int c0 = s * 32 + lq * 8;
#pragma unroll
        for (int nf = 0; nf < 4; ++nf) {
            U4 fr;
#pragma unroll
            for (int j = 0; j < 8; ++j) {
                const unsigned short* hp = reinterpret_cast<const unsigned short*>(
                    hbase_f + (size_t)(c0 + j) * HW);
                const float v = fmaxf(
                    fmaf(bf2f(hp[segoff + nf * 16]), sSB[c0 + j][0], sSB[c0 + j][1]),
                    0.f);
                fr.u[j] = f2bf(v);
            }
            d[nf] = fr.q;
        }
    };
    auto mfma16 = [&](uint4* pa, uint4* pb) {
#pragma unroll
        for (int mf = 0; mf < 4; ++mf) {
            U4 am; am.q = pa[mf];
#pragma unroll
            for (int nf = 0; nf < 4; ++nf) {
                U4 bm; bm.q = pb[nf];
                acc[mf][nf] = __builtin_amdgcn_mfma_f32_16x16x32_bf16(
                    am.v, bm.v, acc[mf][nf], 0, 0, 0);
            }
        }
    };

    loadA(0, pa0);
    loadB(0, pb0);
    // K = 128 -> 4 steps of 32, 2-deep register pipeline
    loadA(1, pa1);
    loadB(1, pb1);
    mfma16(pa0, pb0);
    loadA(2, pa0);
    loadB(2, pb0);
    mfma16(pa1, pb1);
    loadA(3, pa1);
    loadB(3, pb1);
    mfma16(pa0, pb0);
    mfma16(pa1, pb1);

    // RACE FIX: all waves' h-reads must complete before any wave overwrites
    // this pixel block's segments with f32 out (h lives in their low halves).
    __syncthreads();

#pragma unroll
    for (int mf = 0; mf < 4; ++mf) {
#pragma unroll
        for (int reg = 0; reg < 4; ++reg) {
            const int och = wm * 64 + mf * 16 + lq * 4 + reg;
            float* orow = io + (size_t)(b * C + och) * HW + p0;
#pragma unroll
            for (int nf = 0; nf < 4; ++nf)
                orow[wn * 64 + nf * 16 + lr] = acc[mf][nf][reg];
        }
    }
}

extern "C" void kernel_launch(void* const* d_in, const int* in_sizes, int n_in,
                              void* d_out, int out_size, void* d_ws, size_t ws_size,
                              hipStream_t stream) {
    const float* x = (const float*)d_in[0];
    const float* w1 = (const float*)d_in[1];
    const float* gamma = (const float*)d_in[2];
    const float* beta = (const float*)d_in[3];
    const float* w2 = (const float*)d_in[4];
    float* out = (float*)d_out;
    float* ws = (float*)d_ws;
    unsigned short* wt = (unsigned short*)(ws + WS_WT);
    unsigned short* w2t = (unsigned short*)(ws + WS_W2T);

    hipMemsetAsync(d_ws, 0, 98304, stream);
    k_wprep<<<576, 256, 0, stream>>>(w1, wt);
    k_wprep2<<<64, 256, 0, stream>>>(w2, w2t);
    k_sums<<<B * C, 256, 0, stream>>>(x, ws);
    k_gate<<<B, 256, 0, stream>>>(ws);

    if (ws_size >= WS_Y_BYTES_OFF + Y2P_BYTES) {
        unsigned short* y2 = (unsigned short*)((char*)d_ws + WS_Y_BYTES_OFF);
        k_yzero<<<514, 256, 0, stream>>>(y2);
        k_ygenT<<<B * H, 256, 0, stream>>>(x, ws, y2);
        k_conv3g<<<B * 256 * 2, 256, 0, stream>>>(y2, wt, ws, out);
    } else {
        k_conv3<<<B * 256 * 2, 256, 0, stream>>>(x, wt, ws, out);
    }

    k_scalebias<<<1, 128, 0, stream>>>(gamma, beta, ws);
    k_conv1d<<<B * 512, 256, 0, stream>>>(out, w2t, ws);
}

// Round 18
// 505.534 us; speedup vs baseline: 1.0302x; 1.0302x over previous
//
#include <hip/hip_runtime.h>
#include <hip/hip_bf16.h>
#include <math.h>

constexpr int B = 8, C = 128, H = 256, W = 256, NN = 256, KNN = 5;
constexpr int HW = H * W;

// ws float offsets
constexpr int WS_ROWSUM = 0;      // 2048 floats
constexpr int WS_COLSUM = 2048;   // 2048
constexpr int WS_GMUL   = 4096;   // 2048  (1 + gate)
constexpr int WS_SCALE  = 6144;   // 128
constexpr int WS_BIAS   = 6272;   // 128
constexpr int WS_PART   = 8192;   // [128 c][64 slot][2] = 16384 floats
constexpr int WS_WT     = 24576;  // conv3 bf16 weights: 36*128*32 ushort
constexpr int WS_W2T    = 98304;  // conv1 bf16 weights: 4*128*32 ushort
constexpr size_t WS_Y_BYTES_OFF = 512 * 1024;

// padded y2p[b][hp=258][c8=16][wp=258][8] bf16, borders (hp/wp = 0,257) zero
constexpr int Y2P_CS = 258 * 8;            // 2064 shorts per c8 row
constexpr int Y2P_HS = 16 * Y2P_CS;        // 33024 shorts per hp
constexpr int Y2P_BS = 258 * Y2P_HS;       // 8,520,192 shorts per b
constexpr size_t Y2P_BYTES = (size_t)B * Y2P_BS * 2;  // 136,323,072

// h is stored as bf16 in the LOWER HALF of each 128-px f32 segment of d_out
// (block-disjoint with the f32 out write -> in-place discipline unchanged).

typedef __attribute__((ext_vector_type(8))) short bf16x8;
typedef __attribute__((ext_vector_type(4))) float f32x4;

union U4 { uint4 q; bf16x8 v; unsigned short u[8]; };

typedef const __attribute__((address_space(1))) unsigned char* gas1;
typedef __attribute__((address_space(3))) unsigned char* las3;
__device__ __forceinline__ void gl_lds16(const void* g, void* l) {
    __builtin_amdgcn_global_load_lds((gas1)g, (las3)l, 16, 0, 0);
}

__device__ inline unsigned short f2bf(float f) {
    __hip_bfloat16 h = __float2bfloat16(f);
    return *reinterpret_cast<unsigned short*>(&h);
}
__device__ inline float bf2f(unsigned short u) {
    __hip_bfloat16 h = *reinterpret_cast<__hip_bfloat16*>(&u);
    return __bfloat162float(h);
}

// ---------------- fused row+col sums (one pass over x) ---------------------
__global__ __launch_bounds__(256) void k_sums(const float* __restrict__ x,
                                              float* __restrict__ ws) {
    const int b = blockIdx.x >> 7;
    const int c = blockIdx.x & 127;
    const int t = threadIdx.x;
    const int wv = t >> 6;
    const float4* p4 = (const float4*)(x + (size_t)(b * C + c) * HW);
    __shared__ float srow[256];
    __shared__ float scol[4][256];
    float ca0 = 0.f, ca1 = 0.f, ca2 = 0.f, ca3 = 0.f;
    for (int it = 0; it < 64; ++it) {
        const float4 v = p4[it * 256 + t];
        ca0 += v.x; ca1 += v.y; ca2 += v.z; ca3 += v.w;
        float s = v.x + v.y + v.z + v.w;
#pragma unroll
        for (int m = 1; m < 64; m <<= 1) s += __shfl_xor(s, m);
        if ((t & 63) == 0) srow[it * 4 + wv] = s;
    }
    const int cb = (t & 63) * 4;
    scol[wv][cb + 0] = ca0;
    scol[wv][cb + 1] = ca1;
    scol[wv][cb + 2] = ca2;
    scol[wv][cb + 3] = ca3;
    __syncthreads();
    atomicAdd(&ws[WS_ROWSUM + b * 256 + t], srow[t]);
    atomicAdd(&ws[WS_COLSUM + b * 256 + t],
              scol[0][t] + scol[1][t] + scol[2][t] + scol[3][t]);
}

// ---------------- gate -----------------------------------------------------
__global__ void k_gate(float* __restrict__ ws) {
    const int b = blockIdx.x;
    const int i = threadIdx.x;
    __shared__ float xm[256], sgn[256];
    const float v = ws[WS_ROWSUM + b * 256 + i] * (1.f / 32768.f)
                  + ws[WS_COLSUM + b * 256 + i] * (1.f / 32768.f);
    xm[i] = v;
    const float vv = v * 0.5f;
    sgn[i] = vv / fmaxf(fabsf(vv), 1e-12f);
    __syncthreads();
    const float si = sgn[i];
    float bd[KNN];
    int bi[KNN];
    for (int k = 0; k < KNN; ++k) { bd[k] = 1e30f; bi[k] = 0; }
    for (int j = 0; j < NN; ++j) {
        float d = si - sgn[j];
        d *= d;
        if (d < bd[KNN - 1]) {
            int p = KNN - 1;
            while (p > 0 && bd[p - 1] > d) {
                bd[p] = bd[p - 1];
                bi[p] = bi[p - 1];
                --p;
            }
            bd[p] = d;
            bi[p] = j;
        }
    }
    float gs = 0.f;
    for (int k = 0; k < KNN; ++k) gs += xm[bi[k]];
    const float gate = 1.f / (1.f + expf(-gs));
    ws[WS_GMUL + b * 256 + i] = 1.f + gate;
}

// -------- y gen into padded layout + border zeroing (yzero merged) ---------
// block (b,h) writes interior row hp=h+1 and zeroes its border cols wp=0,257;
// blocks with h==0 / h==255 additionally zero border rows hp=0 / hp=257.
__global__ __launch_bounds__(256) void k_ygenT(const float* __restrict__ x,
                                               const float* __restrict__ ws,
                                               unsigned short* __restrict__ y) {
    const int b = blockIdx.x >> 8;
    const int h = blockIdx.x & 255;
    const int w = threadIdx.x;
    const uint4 z = {0u, 0u, 0u, 0u};
    unsigned short* yb = y + (size_t)b * Y2P_BS;

    // border columns of this block's interior row (32 uint4: 16 c8 x 2 cols)
    if (w < 32) {
        const int c8 = w >> 1;
        const int wp = (w & 1) ? 257 : 0;
        *reinterpret_cast<uint4*>(yb + (size_t)(h + 1) * Y2P_HS + c8 * Y2P_CS + wp * 8) = z;
    }
    // border rows hp=0 (h==0 block) / hp=257 (h==255 block): 4128 uint4 each
    if (h == 0) {
        for (int i = w; i < Y2P_HS / 8; i += 256)
            *reinterpret_cast<uint4*>(yb + (size_t)0 * Y2P_HS + i * 8) = z;
    } else if (h == 255) {
        for (int i = w; i < Y2P_HS / 8; i += 256)
            *reinterpret_cast<uint4*>(yb + (size_t)257 * Y2P_HS + i * 8) = z;
    }

    const float g = ws[WS_GMUL + b * 256 + h];
    const float* xp = x + ((size_t)(b * C) * H + h) * W + w;
    unsigned short* yp = yb + (size_t)(h + 1) * Y2P_HS + (w + 1) * 8;
    for (int c8 = 0; c8 < 16; ++c8) {
        U4 pk;
#pragma unroll
        for (int j = 0; j < 8; ++j)
            pk.u[j] = f2bf(xp[(size_t)(c8 * 8 + j) * HW] * g);
        *reinterpret_cast<uint4*>(yp + c8 * Y2P_CS) = pk.q;
    }
}

// ------- conv3 weight pre-transform [s][och][k] (+ conv1 w2 merged) --------
__global__ void k_wprep(const float* __restrict__ w1, unsigned short* __restrict__ wt,
                        const float* __restrict__ w2, unsigned short* __restrict__ w2t) {
    const int e = blockIdx.x * 256 + threadIdx.x;  // 576*256 = 147456
    const int j = e & 7;
    const int kg = (e >> 3) & 3;
    const int och = (e >> 5) & 127;
    const int s = e >> 12;
    const int c = (s & 3) * 32 + kg * 8 + j;
    const int pos = s >> 2;
    const int ky = pos / 3, kx = pos - ky * 3;
    wt[e] = f2bf(w1[(((size_t)och * C + c) * 3 + ky) * 3 + kx]);
    if (e < 16384) {  // conv1 weights: [s2][och][32], c = s2*32+kk
        const int kk = e & 31;
        const int och2 = (e >> 5) & 127;
        const int s2 = e >> 12;
        w2t[e] = f2bf(w2[och2 * C + s2 * 32 + kk]);
    }
}

// ========== conv3, 2-phase pipelined LDS + bank-conflict XOR swizzle =======
// (R16 proven: 261 us, bank conflicts 65K, occupancy 30%.)
__global__ __launch_bounds__(256) void k_conv3g(const unsigned short* __restrict__ y2,
                                                const unsigned short* __restrict__ wt,
                                                float* __restrict__ ws,
                                                float* __restrict__ hout) {
    // XCD-contiguous swizzle: 4096 blocks = 8 XCDs x 512
    const int bx0 = blockIdx.x;
    const int bx = (bx0 & 7) * 512 + (bx0 >> 3);
    const int whalf = bx & 1;
    const int hrow = (bx >> 1) & 255;
    const int b = bx >> 9;
    const int w0 = whalf * 128;

    const int t = threadIdx.x;
    const int wv = t >> 6;
    const int l = t & 63;
    const int wm = wv >> 1, wn = wv & 1;
    const int lr = l & 15, lq = l >> 4;

    __shared__ __attribute__((aligned(16))) unsigned short sA[2][4096];  // [128 och][32 k]
    __shared__ __attribute__((aligned(16))) unsigned short sB[2][4096];  // [128 px][32 k]
    __shared__ float sPart[4][128][2];

    f32x4 acc[4][4];
#pragma unroll
    for (int i = 0; i < 4; ++i)
#pragma unroll
        for (int j = 0; j < 4; ++j) acc[i][j] = (f32x4){0.f, 0.f, 0.f, 0.f};

    const char* wtb = (const char*)wt;
    const char* y2b = (const char*)y2 + (size_t)b * Y2P_BS * 2;
    // bank swizzle: staged k-chunk permuted by k16s; read back with lqs.
    const int k16s = (l & 3) ^ ((l >> 3) & 3);
    const unsigned aLane = (unsigned)((wv * 16 + (l >> 2)) * 64 + k16s * 16);
    const int pxl = wv * 16 + (l >> 2);
    const unsigned bLane0 = (unsigned)((pxl * 8 + k16s * Y2P_CS) * 2);
    const unsigned bLane1 = (unsigned)(((pxl + 64) * 8 + k16s * Y2P_CS) * 2);

    auto stage = [&](int s, char* sAp, char* sBp) {
        const int pos = s >> 2, cc = s & 3;
        const int ky = pos / 3, kx = pos - 3 * ky;
        const char* aSrc = wtb + ((size_t)s << 13);
        const char* bSrc = y2b + (size_t)((hrow + ky) * Y2P_HS + cc * 4 * Y2P_CS
                                          + (w0 + kx) * 8) * 2;
        gl_lds16(aSrc + aLane,        sAp + wv * 1024);
        gl_lds16(aSrc + 4096 + aLane, sAp + 4096 + wv * 1024);
        gl_lds16(bSrc + bLane0,       sBp + wv * 1024);
        gl_lds16(bSrc + bLane1,       sBp + 4096 + wv * 1024);
    };
    auto compute = [&](const unsigned short* aT, const unsigned short* bT) {
        const int lqs = lq ^ ((lr >> 1) & 3);  // read-side inverse swizzle
        const unsigned short* aRd = aT + (wm * 64 + lr) * 32 + lqs * 8;
        const unsigned short* bRd = bT + (wn * 64 + lr) * 32 + lqs * 8;
        bf16x8 af[4], bfr[4];
#pragma unroll
        for (int mf = 0; mf < 4; ++mf)
            af[mf] = *reinterpret_cast<const bf16x8*>(aRd + mf * 512);
#pragma unroll
        for (int nf = 0; nf < 4; ++nf)
            bfr[nf] = *reinterpret_cast<const bf16x8*>(bRd + nf * 512);
#pragma unroll
        for (int mf = 0; mf < 4; ++mf)
#pragma unroll
            for (int nf = 0; nf < 4; ++nf)
                acc[mf][nf] = __builtin_amdgcn_mfma_f32_16x16x32_bf16(
                    af[mf], bfr[nf], acc[mf][nf], 0, 0, 0);
    };

    stage(0, (char*)sA[0], (char*)sB[0]);
    __syncthreads();  // prologue drain: buf0 ready
    for (int s = 0; s < 36; s += 2) {
        if (s + 1 < 36) stage(s + 1, (char*)sA[1], (char*)sB[1]);
        compute(sA[0], sB[0]);
        __syncthreads();
        if (s + 2 < 36) stage(s + 2, (char*)sA[0], (char*)sB[0]);
        compute(sA[1], sB[1]);
        __syncthreads();
    }

    // store h as bf16 packed into the LOW HALF of this 128-px f32 segment.
#pragma unroll
    for (int mf = 0; mf < 4; ++mf) {
#pragma unroll
        for (int reg = 0; reg < 4; ++reg) {
            const int och = wm * 64 + mf * 16 + lq * 4 + reg;
            unsigned short* hseg = reinterpret_cast<unsigned short*>(
                hout + (((size_t)(b * C + och) * H + hrow) * W) + w0);
#pragma unroll
            for (int nf = 0; nf < 4; ++nf)
                hseg[wn * 64 + nf * 16 + lr] = f2bf(acc[mf][nf][reg]);
        }
    }

    // fused BN partial stats (from f32 acc)
#pragma unroll
    for (int mf = 0; mf < 4; ++mf) {
#pragma unroll
        for (int reg = 0; reg < 4; ++reg) {
            float s = 0.f, q = 0.f;
#pragma unroll
            for (int nf = 0; nf < 4; ++nf) {
                const float v = acc[mf][nf][reg];
                s += v;
                q = fmaf(v, v, q);
            }
#pragma unroll
            for (int m = 1; m < 16; m <<= 1) {
                s += __shfl_xor(s, m);
                q += __shfl_xor(q, m);
            }
            if (lr == 0) {
                const int och = wm * 64 + mf * 16 + lq * 4 + reg;
                sPart[wv][och][0] = s;
                sPart[wv][och][1] = q;
            }
        }
    }
    __syncthreads();
    {
        const int o = t & 127;
        const int which = t >> 7;
        const int wmn = o >> 6;
        const float v = sPart[wmn * 2][o][which] + sPart[wmn * 2 + 1][o][which];
        atomicAdd(&ws[WS_PART + o * 128 + (bx & 63) * 2 + which], v);
    }
}

// ---------------- SLOW-PATH conv3 (reads f32 x; bf16 h store) --------------
__device__ inline bf16x8 b_fetch(const float* __restrict__ x, int b, int s,
                                 int hrow, int w0, int px, int kg,
                                 float g0, float g1, float g2) {
    const int pos = s >> 2;
    const int ky = pos / 3, kx = pos - ky * 3;
    const int cbase = (s & 3) * 32 + kg * 8;
    int crow = hrow + ky - 1;
    int col = w0 + px + kx - 1;
    const float g = (ky == 0) ? g0 : ((ky == 1) ? g1 : g2);
    const float sc = ((unsigned)col < (unsigned)W) ? g : 0.f;
    crow = min(max(crow, 0), H - 1);
    col = min(max(col, 0), W - 1);
    const float* p = x + (((size_t)(b * C + cbase) * H + crow) * W + col);
    union { bf16x8 v8; unsigned short u[8]; } r;
#pragma unroll
    for (int j = 0; j < 8; ++j) r.u[j] = f2bf(p[(size_t)j * HW] * sc);
    return r.v8;
}

__global__ __launch_bounds__(256) void k_conv3(const float* __restrict__ x,
                                               const unsigned short* __restrict__ wt,
                                               float* __restrict__ ws,
                                               float* __restrict__ hout) {
    const int bx = blockIdx.x;
    const int whalf = bx & 1;
    const int hrow = (bx >> 1) & 255;
    const int b = bx >> 9;
    const int w0 = whalf * 128;

    const int t = threadIdx.x;
    const int wv = t >> 6;
    const int l = t & 63;
    const int wm = wv >> 1, wn = wv & 1;
    const int lr = l & 15, lq = l >> 4;

    __shared__ unsigned short sA[128 * 40];
    __shared__ unsigned short sB[128 * 40];
    __shared__ float sPart[4][128][2];

    float g0, g1, g2;
    {
        const int r0 = hrow - 1, r2 = hrow + 1;
        g0 = (r0 >= 0) ? ws[WS_GMUL + b * 256 + r0] : 0.f;
        g1 = ws[WS_GMUL + b * 256 + hrow];
        g2 = (r2 < H) ? ws[WS_GMUL + b * 256 + r2] : 0.f;
    }

    f32x4 acc[4][4];
#pragma unroll
    for (int i = 0; i < 4; ++i)
#pragma unroll
        for (int j = 0; j < 4; ++j) acc[i][j] = (f32x4){0.f, 0.f, 0.f, 0.f};

    const int a_och = t & 127, a_h = t >> 7;
    const int b_px = t & 127, b_kg0 = t >> 7;
    const int b_kg1 = b_kg0 + 2;

    uint4 pa0, pa1;
    bf16x8 pb0, pb1;
    {
        const uint4* asrc = reinterpret_cast<const uint4*>(wt + (size_t)a_och * 32 + a_h * 16);
        pa0 = asrc[0];
        pa1 = asrc[1];
        pb0 = b_fetch(x, b, 0, hrow, w0, b_px, b_kg0, g0, g1, g2);
        pb1 = b_fetch(x, b, 0, hrow, w0, b_px, b_kg1, g0, g1, g2);
    }

    for (int s = 0; s < 36; ++s) {
        __syncthreads();
        *reinterpret_cast<uint4*>(&sA[a_och * 40 + a_h * 16]) = pa0;
        *reinterpret_cast<uint4*>(&sA[a_och * 40 + a_h * 16 + 8]) = pa1;
        *reinterpret_cast<bf16x8*>(&sB[b_px * 40 + b_kg0 * 8]) = pb0;
        *reinterpret_cast<bf16x8*>(&sB[b_px * 40 + b_kg1 * 8]) = pb1;
        __syncthreads();

        if (s + 1 < 36) {
            const uint4* asrc = reinterpret_cast<const uint4*>(
                wt + (size_t)(s + 1) * 4096 + (size_t)a_och * 32 + a_h * 16);
            pa0 = asrc[0];
            pa1 = asrc[1];
            pb0 = b_fetch(x, b, s + 1, hrow, w0, b_px, b_kg0, g0, g1, g2);
            pb1 = b_fetch(x, b, s + 1, hrow, w0, b_px, b_kg1, g0, g1, g2);
        }

        bf16x8 af[4], bfr[4];
#pragma unroll
        for (int mf = 0; mf < 4; ++mf) {
            const int och = wm * 64 + mf * 16 + lr;
            af[mf] = *reinterpret_cast<const bf16x8*>(&sA[och * 40 + lq * 8]);
        }
#pragma unroll
        for (int nf = 0; nf < 4; ++nf) {
            const int px = wn * 64 + nf * 16 + lr;
            bfr[nf] = *reinterpret_cast<const bf16x8*>(&sB[px * 40 + lq * 8]);
        }
#pragma unroll
        for (int mf = 0; mf < 4; ++mf)
#pragma unroll
            for (int nf = 0; nf < 4; ++nf)
                acc[mf][nf] = __builtin_amdgcn_mfma_f32_16x16x32_bf16(
                    af[mf], bfr[nf], acc[mf][nf], 0, 0, 0);
    }

#pragma unroll
    for (int mf = 0; mf < 4; ++mf) {
#pragma unroll
        for (int reg = 0; reg < 4; ++reg) {
            const int och = wm * 64 + mf * 16 + lq * 4 + reg;
            unsigned short* hseg = reinterpret_cast<unsigned short*>(
                hout + (((size_t)(b * C + och) * H + hrow) * W) + w0);
#pragma unroll
            for (int nf = 0; nf < 4; ++nf)
                hseg[wn * 64 + nf * 16 + lr] = f2bf(acc[mf][nf][reg]);
        }
    }

#pragma unroll
    for (int mf = 0; mf < 4; ++mf) {
#pragma unroll
        for (int reg = 0; reg < 4; ++reg) {
            float s = 0.f, q = 0.f;
#pragma unroll
            for (int nf = 0; nf < 4; ++nf) {
                const float v = acc[mf][nf][reg];
                s += v;
                q = fmaf(v, v, q);
            }
#pragma unroll
            for (int m = 1; m < 16; m <<= 1) {
                s += __shfl_xor(s, m);
                q += __shfl_xor(q, m);
            }
            if (lr == 0) {
                const int och = wm * 64 + mf * 16 + lq * 4 + reg;
                sPart[wv][och][0] = s;
                sPart[wv][och][1] = q;
            }
        }
    }
    __syncthreads();
    {
        const int o = t & 127;
        const int which = t >> 7;
        const int wmn = o >> 6;
        const float v = sPart[wmn * 2][o][which] + sPart[wmn * 2 + 1][o][which];
        atomicAdd(&ws[WS_PART + o * 128 + (bx & 63) * 2 + which], v);
    }
}

// ---------------- BN scale/bias from partials ------------------------------
__global__ void k_scalebias(const float* __restrict__ gamma,
                            const float* __restrict__ beta, float* __restrict__ ws) {
    const int c = threadIdx.x;
    const float* p = ws + WS_PART + c * 128;
    float s = 0.f, q = 0.f;
    for (int i = 0; i < 64; ++i) {
        s += p[i * 2];
        q += p[i * 2 + 1];
    }
    const float cnt = (float)B * HW;
    const float mu = s / cnt;
    const float var = q / cnt - mu * mu;
    const float rs = rsqrtf(var + 1e-5f);
    const float sc = rs * gamma[c];
    ws[WS_SCALE + c] = sc;
    ws[WS_BIAS + c] = beta[c] - mu * sc;
}

// ========== conv1: plain bf16 operands, K=128 (4 steps), in place ==========
__global__ __launch_bounds__(256) void k_conv1d(float* __restrict__ io,
                                                const unsigned short* __restrict__ w2t,
                                                const float* __restrict__ ws) {
    const int bx = blockIdx.x;
    const int pblk = bx & 511;
    const int b = bx >> 9;
    const size_t p0 = (size_t)pblk * 128;

    const int t = threadIdx.x;
    const int wv = t >> 6;
    const int l = t & 63;
    const int wm = wv >> 1, wn = wv & 1;
    const int lr = l & 15, lq = l >> 4;

    __shared__ float sSB[128][2];
    if (t < 128) {
        sSB[t][0] = ws[WS_SCALE + t];
        sSB[t][1] = ws[WS_BIAS + t];
    }
    __syncthreads();

    f32x4 acc[4][4];
#pragma unroll
    for (int i = 0; i < 4; ++i)
#pragma unroll
        for (int j = 0; j < 4; ++j) acc[i][j] = (f32x4){0.f, 0.f, 0.f, 0.f};

    const unsigned aoff = (unsigned)((wm * 64 + lr) * 32 + lq * 8);
    const float* hbase_f = io + (size_t)b * C * HW + p0;  // + c*HW per channel
    const int segoff = wn * 64 + lr;                      // + nf*16

    uint4 pa0[4], pb0[4], pa1[4], pb1[4];

    auto loadA = [&](int s, uint4* d) {
        const unsigned so = aoff + (unsigned)(s * 4096);
#pragma unroll
        for (int mf = 0; mf < 4; ++mf)
            d[mf] = *reinterpret_cast<const uint4*>(w2t + so + mf * 512);
    };
    auto loadB = [&](int s, uint4* d) {
        const int c0 = s * 32 + lq * 8;
#pragma unroll
        for (int nf = 0; nf < 4; ++nf) {
            U4 fr;
#pragma unroll
            for (int j = 0; j < 8; ++j) {
                const unsigned short* hp = reinterpret_cast<const unsigned short*>(
                    hbase_f + (size_t)(c0 + j) * HW);
                const float v = fmaxf(
                    fmaf(bf2f(hp[segoff + nf * 16]), sSB[c0 + j][0], sSB[c0 + j][1]),
                    0.f);
                fr.u[j] = f2bf(v);
            }
            d[nf] = fr.q;
        }
    };
    auto mfma16 = [&](uint4* pa, uint4* pb) {
#pragma unroll
        for (int mf = 0; mf < 4; ++mf) {
            U4 am; am.q = pa[mf];
#pragma unroll
            for (int nf = 0; nf < 4; ++nf) {
                U4 bm; bm.q = pb[nf];
                acc[mf][nf] = __builtin_amdgcn_mfma_f32_16x16x32_bf16(
                    am.v, bm.v, acc[mf][nf], 0, 0, 0);
            }
        }
    };

    loadA(0, pa0);
    loadB(0, pb0);
    loadA(1, pa1);
    loadB(1, pb1);
    mfma16(pa0, pb0);
    loadA(2, pa0);
    loadB(2, pb0);
    mfma16(pa1, pb1);
    loadA(3, pa1);
    loadB(3, pb1);
    mfma16(pa0, pb0);
    mfma16(pa1, pb1);

    // RACE FIX: all waves' h-reads must complete before any wave overwrites
    // this pixel block's segments with f32 out (h lives in their low halves).
    __syncthreads();

#pragma unroll
    for (int mf = 0; mf < 4; ++mf) {
#pragma unroll
        for (int reg = 0; reg < 4; ++reg) {
            const int och = wm * 64 + mf * 16 + lq * 4 + reg;
            float* orow = io + (size_t)(b * C + och) * HW + p0;
#pragma unroll
            for (int nf = 0; nf < 4; ++nf)
                orow[wn * 64 + nf * 16 + lr] = acc[mf][nf][reg];
        }
    }
}

extern "C" void kernel_launch(void* const* d_in, const int* in_sizes, int n_in,
                              void* d_out, int out_size, void* d_ws, size_t ws_size,
                              hipStream_t stream) {
    const float* x = (const float*)d_in[0];
    const float* w1 = (const float*)d_in[1];
    const float* gamma = (const float*)d_in[2];
    const float* beta = (const float*)d_in[3];
    const float* w2 = (const float*)d_in[4];
    float* out = (float*)d_out;
    float* ws = (float*)d_ws;
    unsigned short* wt = (unsigned short*)(ws + WS_WT);
    unsigned short* w2t = (unsigned short*)(ws + WS_W2T);

    hipMemsetAsync(d_ws, 0, 98304, stream);
    k_wprep<<<576, 256, 0, stream>>>(w1, wt, w2, w2t);
    k_sums<<<B * C, 256, 0, stream>>>(x, ws);
    k_gate<<<B, 256, 0, stream>>>(ws);

    if (ws_size >= WS_Y_BYTES_OFF + Y2P_BYTES) {
        unsigned short* y2 = (unsigned short*)((char*)d_ws + WS_Y_BYTES_OFF);
        k_ygenT<<<B * H, 256, 0, stream>>>(x, ws, y2);
        k_conv3g<<<B * 256 * 2, 256, 0, stream>>>(y2, wt, ws, out);
    } else {
        k_conv3<<<B * 256 * 2, 256, 0, stream>>>(x, wt, ws, out);
    }

    k_scalebias<<<1, 128, 0, stream>>>(gamma, beta, ws);
    k_conv1d<<<B * 512, 256, 0, stream>>>(out, w2t, ws);
}